// Round 7
// baseline (175.715 us; speedup 1.0000x reference)
//
#include <hip/hip_runtime.h>
#include <math.h>

constexpr int NSUP = 3072;            // B*S images
constexpr float EPSF = 1e-5f;

// Workspace layout (float offsets)
constexpr int WS_W1B  = 0;            // bf16 [kt2][oc32][k32] conv1(x)pool composite -> 1024 f
constexpr int WS_B1   = 1024;         // fp32 32
constexpr int WS_W2B  = 1056;         // bf16 [tap9][oc32][ic32] = 9216 ush = 4608 f
constexpr int WS_W3B  = 5664;         // same
constexpr int WS_W4B  = 10272;        // bf16 [tap9][ic32] = 288 ush = 144 f
constexpr int WS_B4   = 10416;        // fp32 1 (+pad)
constexpr int WS_B2   = 10420;        // fp32 32
constexpr int WS_B3   = 10452;        // fp32 32
constexpr int WS_HW1  = 10484;        // bf16 [64][72] = 4608 ush = 2304 f
constexpr int WS_HW2  = 12788;
constexpr int WS_HRQ  = 15092;
constexpr int WS_HROT = 17396;        // ro^T
constexpr int WS_PART = 19700;        // [512] loss, [512] correct
constexpr int WS_FEATS= 20724;        // 4096*64 f32

using short8 = __attribute__((ext_vector_type(8))) short;
using f32x4  = __attribute__((ext_vector_type(4))) float;

__device__ __forceinline__ float gelu_f(float x) {
    return 0.5f * x * (1.0f + erff(x * 0.70710678118654752440f));
}
__device__ __forceinline__ unsigned short f2bf(float f) {
    unsigned u = __float_as_uint(f);
    return (unsigned short)((u + 0x7FFFu + ((u >> 16) & 1u)) >> 16);
}
__device__ __forceinline__ float bflo(unsigned u) { return __uint_as_float(u << 16); }
__device__ __forceinline__ float bfhi(unsigned u) { return __uint_as_float(u & 0xffff0000u); }

// ---------------------------------------------------------------------------
// Precompute: fold BN; emit bf16 MFMA layouts for all conv + head weights.
// ---------------------------------------------------------------------------
__global__ void __launch_bounds__(256) precompute_kernel(
    const float* __restrict__ c1w, const float* __restrict__ c1b, const float* __restrict__ bn1,
    const float* __restrict__ c2w, const float* __restrict__ c2b, const float* __restrict__ bn2,
    const float* __restrict__ c3w, const float* __restrict__ c3b, const float* __restrict__ bn3,
    const float* __restrict__ c4w, const float* __restrict__ c4b, const float* __restrict__ bn4,
    const float* __restrict__ w1, const float* __restrict__ w2,
    const float* __restrict__ rq, const float* __restrict__ ro,
    float* __restrict__ ws)
{
    const int gid = blockIdx.x * 256 + threadIdx.x;
    const int gsz = gridDim.x * 256;

    // conv1 composite B: [kt][oc][k] with k=tap (0..35), zero-padded
    unsigned short* w1b = (unsigned short*)(ws + WS_W1B);
    for (int v = gid; v < 2048; v += gsz) {
        int kt = v >> 10, rem = v & 1023, oc = rem >> 5, kk = rem & 31;
        int tap = kt * 32 + kk;
        unsigned short o = 0;
        if (tap < 36) {
            int tt = tap / 6, s = tap - tt * 6;
            float sum = 0.f;
            for (int di = 0; di < 3; ++di) {
                int a = tt - di; if (a < 0 || a > 3) continue;
                for (int dj = 0; dj < 3; ++dj) {
                    int bb = s - dj; if (bb < 0 || bb > 3) continue;
                    sum += c1w[oc * 9 + di * 3 + dj];
                }
            }
            float sc1 = bn1[oc] * rsqrtf(bn1[96 + oc] + EPSF);
            o = f2bf(sum * sc1 * (1.0f / 16.0f));
        }
        w1b[v] = o;
    }
    for (int c = gid; c < 32; c += gsz) {
        float sc1 = bn1[c] * rsqrtf(bn1[96 + c] + EPSF);
        ws[WS_B1 + c] = (c1b[c] - bn1[64 + c]) * sc1 + bn1[32 + c];
        float sc2 = bn2[c] * rsqrtf(bn2[96 + c] + EPSF);
        ws[WS_B2 + c] = (c2b[c] - bn2[64 + c]) * sc2 + bn2[32 + c];
        float sc3 = bn3[c] * rsqrtf(bn3[96 + c] + EPSF);
        ws[WS_B3 + c] = (c3b[c] - bn3[64 + c]) * sc3 + bn3[32 + c];
    }
    // conv2/3: [tap][oc][ic] bf16
    unsigned short* w2b = (unsigned short*)(ws + WS_W2B);
    unsigned short* w3b = (unsigned short*)(ws + WS_W3B);
    for (int v = gid; v < 9216; v += gsz) {
        int tap = v >> 10, oc = (v >> 5) & 31, ic = v & 31;
        float sc2 = bn2[oc] * rsqrtf(bn2[96 + oc] + EPSF);
        float sc3 = bn3[oc] * rsqrtf(bn3[96 + oc] + EPSF);
        w2b[v] = f2bf(c2w[oc * 288 + ic * 9 + tap] * sc2);
        w3b[v] = f2bf(c3w[oc * 288 + ic * 9 + tap] * sc3);
    }
    {
        unsigned short* w4b = (unsigned short*)(ws + WS_W4B);
        float sc4 = bn4[0] * rsqrtf(bn4[3] + EPSF);
        for (int v = gid; v < 288; v += gsz) {
            int tap = v >> 5, ic = v & 31;
            w4b[v] = f2bf(c4w[ic * 9 + tap] * sc4);
        }
        if (gid == 0) ws[WS_B4] = (c4b[0] - bn4[2]) * sc4 + bn4[1];
    }
    // head weights bf16 [64][72]
    unsigned short* hw1 = (unsigned short*)(ws + WS_HW1);
    unsigned short* hw2 = (unsigned short*)(ws + WS_HW2);
    unsigned short* hrq = (unsigned short*)(ws + WS_HRQ);
    unsigned short* hro = (unsigned short*)(ws + WS_HROT);
    for (int v = gid; v < 4608; v += gsz) {
        int e = v / 72, d = v - e * 72;
        unsigned short a = 0, b = 0, c = 0, r = 0;
        if (d < 64) {
            a = f2bf(w1[e * 64 + d]);
            b = f2bf(w2[e * 64 + d]);
            c = f2bf(rq[e * 64 + d]);
            r = f2bf(ro[d * 64 + e]);
        }
        hw1[v] = a; hw2[v] = b; hrq[v] = c; hro[v] = r;
    }
}

// ---------------------------------------------------------------------------
// feats: 256 threads = 4 waves = 4 images. Full-MFMA conv stack, barrier-free
// (act buffers are wave-private; weights read from L1/L2-hot global).
// Act buffer per image: [10 rows][10 cols][32 ch] bf16 (halo zeros).
// ---------------------------------------------------------------------------
__global__ void __launch_bounds__(256, 4) feats_kernel(
    const float* __restrict__ sxs, const float* __restrict__ qxs,
    const float* __restrict__ lin_w, const float* __restrict__ ws,
    float* __restrict__ feats)
{
    __shared__ __align__(16) unsigned short sAct[4][3200];
    __shared__ __align__(16) float sh4[4][64];

    const int t    = threadIdx.x;
    const int wv   = t >> 6;
    const int lane = t & 63;
    const int col  = lane & 15;
    const int quad = lane >> 4;
    const int n    = blockIdx.x * 4 + wv;

    unsigned short* A = sAct[wv];

    {   // zero own act buffer (wave-private): 3200 ush = 400 uint4
        uint4 z = {0, 0, 0, 0};
        for (int i = lane; i < 400; i += 64) ((uint4*)A)[i] = z;
    }

    // ---- Stage 1: conv1+bn1+pool+gelu as 64x32xK36 MFMA GEMM ----
    {
        const unsigned short* w1b = (const unsigned short*)(ws + WS_W1B);
        const float* img = (n < NSUP) ? (sxs + (size_t)n * 784) : (qxs + (size_t)(n - NSUP) * 784);
        int ttj[8], ssj[8];
        #pragma unroll
        for (int j = 0; j < 8; ++j) {
            int k = quad * 8 + j;
            ttj[j] = k / 6; ssj[j] = k - ttj[j] * 6;
        }
        f32x4 acc[4][2];
        #pragma unroll
        for (int mt = 0; mt < 4; ++mt) { acc[mt][0] = (f32x4){0,0,0,0}; acc[mt][1] = (f32x4){0,0,0,0}; }

        short8 b00 = *(const short8*)(w1b + (0 * 16 + col) * 32 + quad * 8);
        short8 b01 = *(const short8*)(w1b + (1 * 16 + col) * 32 + quad * 8);
        short8 b10 = *(const short8*)(w1b + 1024 + (0 * 16 + col) * 32 + quad * 8);
        short8 b11 = *(const short8*)(w1b + 1024 + (1 * 16 + col) * 32 + quad * 8);

        #pragma unroll
        for (int mt = 0; mt < 4; ++mt) {
            int px = mt * 16 + col;
            int sr = (((px >> 3) * 7) >> 1) - 1;
            int sc = (((px & 7) * 7) >> 1) - 1;
            short8 a0;
            #pragma unroll
            for (int j = 0; j < 8; ++j) {
                int rr = sr + ttj[j], cc = sc + ssj[j];
                float v = ((unsigned)rr < 28u && (unsigned)cc < 28u) ? img[rr * 28 + cc] : 0.f;
                a0[j] = (short)f2bf(v);
            }
            acc[mt][0] = __builtin_amdgcn_mfma_f32_16x16x32_bf16(a0, b00, acc[mt][0], 0, 0, 0);
            acc[mt][1] = __builtin_amdgcn_mfma_f32_16x16x32_bf16(a0, b01, acc[mt][1], 0, 0, 0);
            short8 a1 = {0,0,0,0,0,0,0,0};
            if (quad == 0) {
                #pragma unroll
                for (int j = 0; j < 4; ++j) {          // k=32..35 -> tt=5, ss=2+j
                    int rr = sr + 5, cc = sc + 2 + j;
                    float v = ((unsigned)rr < 28u && (unsigned)cc < 28u) ? img[rr * 28 + cc] : 0.f;
                    a1[j] = (short)f2bf(v);
                }
            }
            acc[mt][0] = __builtin_amdgcn_mfma_f32_16x16x32_bf16(a1, b10, acc[mt][0], 0, 0, 0);
            acc[mt][1] = __builtin_amdgcn_mfma_f32_16x16x32_bf16(a1, b11, acc[mt][1], 0, 0, 0);
        }
        float bi0 = ws[WS_B1 + col], bi1 = ws[WS_B1 + 16 + col];
        #pragma unroll
        for (int mt = 0; mt < 4; ++mt)
            #pragma unroll
            for (int reg = 0; reg < 4; ++reg) {
                int px = mt * 16 + quad * 4 + reg;
                unsigned short* dst = A + (((px >> 3) + 1) * 10 + (px & 7) + 1) * 32;
                dst[col]      = f2bf(gelu_f(acc[mt][0][reg] + bi0));
                dst[col + 16] = f2bf(gelu_f(acc[mt][1][reg] + bi1));
            }
    }

    // ---- conv2 / conv3: in-place MFMA, weights from global ----
    #pragma unroll 1
    for (int layer = 0; layer < 2; ++layer) {
        const unsigned short* wb = (const unsigned short*)(ws + (layer ? WS_W3B : WS_W2B));
        f32x4 acc[4][2];
        #pragma unroll
        for (int mt = 0; mt < 4; ++mt) { acc[mt][0] = (f32x4){0,0,0,0}; acc[mt][1] = (f32x4){0,0,0,0}; }
        const unsigned short* abase[4];
        #pragma unroll
        for (int mt = 0; mt < 4; ++mt) {
            int px = mt * 16 + col;
            abase[mt] = A + ((px >> 3) * 10 + (px & 7)) * 32 + quad * 8;
        }
        #pragma unroll
        for (int dr = 0; dr < 3; ++dr)
            #pragma unroll
            for (int dc = 0; dc < 3; ++dc) {
                int tap = dr * 3 + dc;
                short8 b0 = *(const short8*)(wb + (tap * 32 + col) * 32 + quad * 8);
                short8 b1 = *(const short8*)(wb + (tap * 32 + 16 + col) * 32 + quad * 8);
                #pragma unroll
                for (int mt = 0; mt < 4; ++mt) {
                    short8 a = *(const short8*)(abase[mt] + (dr * 10 + dc) * 32);
                    acc[mt][0] = __builtin_amdgcn_mfma_f32_16x16x32_bf16(a, b0, acc[mt][0], 0, 0, 0);
                    acc[mt][1] = __builtin_amdgcn_mfma_f32_16x16x32_bf16(a, b1, acc[mt][1], 0, 0, 0);
                }
            }
        float bi0 = ws[(layer ? WS_B3 : WS_B2) + col];
        float bi1 = ws[(layer ? WS_B3 : WS_B2) + 16 + col];
        #pragma unroll
        for (int mt = 0; mt < 4; ++mt)
            #pragma unroll
            for (int reg = 0; reg < 4; ++reg) {
                int px = mt * 16 + quad * 4 + reg;
                unsigned short* dst = A + (((px >> 3) + 1) * 10 + (px & 7) + 1) * 32;
                dst[col]      = f2bf(gelu_f(acc[mt][0][reg] + bi0));
                dst[col + 16] = f2bf(gelu_f(acc[mt][1][reg] + bi1));
            }
    }

    // ---- conv4 (32->1) via broadcast-B MFMA ----
    {
        f32x4 acc4[4];
        #pragma unroll
        for (int mt = 0; mt < 4; ++mt) acc4[mt] = (f32x4){0,0,0,0};
        const unsigned short* abase[4];
        #pragma unroll
        for (int mt = 0; mt < 4; ++mt) {
            int px = mt * 16 + col;
            abase[mt] = A + ((px >> 3) * 10 + (px & 7)) * 32 + quad * 8;
        }
        const unsigned short* w4g = (const unsigned short*)(ws + WS_W4B);
        #pragma unroll
        for (int dr = 0; dr < 3; ++dr)
            #pragma unroll
            for (int dc = 0; dc < 3; ++dc) {
                int tap = dr * 3 + dc;
                short8 b = *(const short8*)(w4g + tap * 32 + quad * 8);
                #pragma unroll
                for (int mt = 0; mt < 4; ++mt) {
                    short8 a = *(const short8*)(abase[mt] + (dr * 10 + dc) * 32);
                    acc4[mt] = __builtin_amdgcn_mfma_f32_16x16x32_bf16(a, b, acc4[mt], 0, 0, 0);
                }
            }
        if (col < 4) {
            f32x4 v = acc4[0];
            if (col == 1) v = acc4[1];
            else if (col == 2) v = acc4[2];
            else if (col == 3) v = acc4[3];
            float b4 = ws[WS_B4];
            #pragma unroll
            for (int reg = 0; reg < 4; ++reg)
                sh4[wv][col * 16 + quad * 4 + reg] = gelu_f(v[reg] + b4);
        }
    }

    // ---- Linear 64x64 fp32 (sh4[wv] is wave-private) ----
    {
        const float4* lw = (const float4*)(lin_w + (size_t)lane * 64);
        const float4* hp = (const float4*)sh4[wv];
        float acc = 0.f;
        #pragma unroll
        for (int j = 0; j < 16; ++j) {
            float4 w = lw[j], h = hp[j];
            acc += w.x * h.x + w.y * h.y + w.z * h.z + w.w * h.w;
        }
        feats[n * 64 + lane] = acc;
    }
}

// ---------------------------------------------------------------------------
// head: 1 batch element per block, 256 threads, bf16 MFMA GEMMs, B-operands
// read from L1/L2-hot global. LDS ~17 KB -> 4 blocks/CU.
// ---------------------------------------------------------------------------
__device__ __forceinline__ void head_gemm(const unsigned short* __restrict__ Ab,   // LDS [32][72]
                                          const unsigned short* __restrict__ Bw,   // global [64][72]
                                          int col, int quad, int wvid, f32x4 res[2])
{
    #pragma unroll
    for (int u = 0; u < 2; ++u) {
        int tau = wvid + u * 4;
        int mt = tau & 1, nt = tau >> 1;
        f32x4 acc = {0, 0, 0, 0};
        #pragma unroll
        for (int kt = 0; kt < 2; ++kt) {
            short8 a = *(const short8*)(Ab + (mt * 16 + col) * 72 + kt * 32 + quad * 8);
            short8 b = *(const short8*)(Bw + (nt * 16 + col) * 72 + kt * 32 + quad * 8);
            acc = __builtin_amdgcn_mfma_f32_16x16x32_bf16(a, b, acc, 0, 0, 0);
        }
        res[u] = acc;
    }
}

__global__ void __launch_bounds__(256, 4) head_kernel(
    const float* __restrict__ emb, const float* __restrict__ tags,
    const float* __restrict__ rk, const float* __restrict__ rv,
    const float* __restrict__ lnw, const float* __restrict__ lnb,
    const int* __restrict__ sys, const int* __restrict__ qys,
    const float* __restrict__ ws, const float* __restrict__ feats,
    float* __restrict__ part)
{
    __shared__ __align__(16) unsigned short bufA[2304], bufB[2304];
    __shared__ __align__(16) float sXf[1536];
    __shared__ __align__(16) float s_xq[128], s_ah[128], s_yp[128];
    __shared__ float s_t1[12], s_t2[12], s_mu[24], s_rs[24], s_lg[4];

    const int t    = threadIdx.x;
    const int b    = blockIdx.x;
    const int wvid = t >> 6;
    const int col  = t & 15;
    const int quad = (t >> 4) & 3;

    const unsigned short* W1g = (const unsigned short*)(ws + WS_HW1);
    const unsigned short* W2g = (const unsigned short*)(ws + WS_HW2);
    const unsigned short* RQg = (const unsigned short*)(ws + WS_HRQ);
    const unsigned short* ROg = (const unsigned short*)(ws + WS_HROT);

    if (t < 72) {   // zero pad rows 24..31 (576 ush = 72 uint4 each)
        uint4 z = {0, 0, 0, 0};
        ((uint4*)(bufA + 1728))[t] = z;
        ((uint4*)(bufB + 1728))[t] = z;
    }
    // tokens (fp32 + bf16)
    for (int idx = t; idx < 1536; idx += 256) {
        int k = idx >> 6, e = idx & 63;
        int s = k >> 2, tg = k & 3;
        int cls = sys[b * 6 + s];
        float v = feats[(b * 6 + s) * 64 + e] + emb[cls * 64 + e] + tags[tg * 64 + e];
        sXf[idx] = v;
        bufA[k * 72 + e] = f2bf(v);
    }
    __syncthreads();

    f32x4 r[2];
    // GEMM1: ah = gelu(X @ w1^T) -> bufB
    head_gemm(bufA, W1g, col, quad, wvid, r);
    #pragma unroll
    for (int u = 0; u < 2; ++u) {
        int tau = wvid + u * 4, mt = tau & 1, nt = tau >> 1;
        #pragma unroll
        for (int reg = 0; reg < 4; ++reg) {
            int row = mt * 16 + quad * 4 + reg;
            if (row < 24) bufB[row * 72 + nt * 16 + col] = f2bf(gelu_f(r[u][reg]));
        }
    }
    __syncthreads();
    // GEMM2: q = ah @ w2^T -> bufA
    head_gemm(bufB, W2g, col, quad, wvid, r);
    #pragma unroll
    for (int u = 0; u < 2; ++u) {
        int tau = wvid + u * 4, mt = tau & 1, nt = tau >> 1;
        #pragma unroll
        for (int reg = 0; reg < 4; ++reg) {
            int row = mt * 16 + quad * 4 + reg;
            if (row < 24) bufA[row * 72 + nt * 16 + col] = f2bf(r[u][reg]);
        }
    }
    __syncthreads();
    // GEMM3: qh = q @ rq^T -> bufB
    head_gemm(bufA, RQg, col, quad, wvid, r);
    #pragma unroll
    for (int u = 0; u < 2; ++u) {
        int tau = wvid + u * 4, mt = tau & 1, nt = tau >> 1;
        #pragma unroll
        for (int reg = 0; reg < 4; ++reg) {
            int row = mt * 16 + quad * 4 + reg;
            if (row < 24) bufB[row * 72 + nt * 16 + col] = f2bf(r[u][reg]);
        }
    }
    __syncthreads();

    // attention over 16 slots per (k, head) -> lor bf16 in bufA
    if (t < 96) {
        int k = t >> 2, nn = t & 3;
        const unsigned short* qp = bufB + k * 72 + nn * 16;
        uint4 u0 = *(const uint4*)(qp);
        uint4 u1 = *(const uint4*)(qp + 8);
        float qv[16];
        qv[0]=bflo(u0.x); qv[1]=bfhi(u0.x); qv[2]=bflo(u0.y); qv[3]=bfhi(u0.y);
        qv[4]=bflo(u0.z); qv[5]=bfhi(u0.z); qv[6]=bflo(u0.w); qv[7]=bfhi(u0.w);
        qv[8]=bflo(u1.x); qv[9]=bfhi(u1.x); qv[10]=bflo(u1.y); qv[11]=bfhi(u1.y);
        qv[12]=bflo(u1.z); qv[13]=bfhi(u1.z); qv[14]=bflo(u1.w); qv[15]=bfhi(u1.w);
        float sc[16]; float mx = -1e30f;
        #pragma unroll
        for (int rr = 0; rr < 16; ++rr) {
            const float* kp = rk + rr * 64 + nn * 16;
            float d = 0.f;
            #pragma unroll
            for (int h = 0; h < 16; ++h) d += qv[h] * kp[h];
            d *= 0.25f;
            sc[rr] = d; mx = fmaxf(mx, d);
        }
        float sum = 0.f;
        #pragma unroll
        for (int rr = 0; rr < 16; ++rr) { sc[rr] = expf(sc[rr] - mx); sum += sc[rr]; }
        float inv = 1.0f / sum;
        float o[16];
        #pragma unroll
        for (int h = 0; h < 16; ++h) o[h] = 0.f;
        #pragma unroll
        for (int rr = 0; rr < 16; ++rr) {
            const float* vp = rv + rr * 64 + nn * 16;
            float p = sc[rr];
            #pragma unroll
            for (int h = 0; h < 16; ++h) o[h] += p * vp[h];
        }
        unsigned short* op = bufA + k * 72 + nn * 16;
        #pragma unroll
        for (int h = 0; h < 16; ++h) op[h] = f2bf(o[h] * inv);
    }
    __syncthreads();

    // GEMM4: z = x + lor @ ro -> sXf (in-place)
    head_gemm(bufA, ROg, col, quad, wvid, r);
    #pragma unroll
    for (int u = 0; u < 2; ++u) {
        int tau = wvid + u * 4, mt = tau & 1, nt = tau >> 1;
        #pragma unroll
        for (int reg = 0; reg < 4; ++reg) {
            int row = mt * 16 + quad * 4 + reg;
            if (row < 24) {
                int idx = row * 64 + nt * 16 + col;
                sXf[idx] = sXf[idx] + r[u][reg];
            }
        }
    }
    __syncthreads();

    // LayerNorm stats
    if (t < 24) {
        const float4* zp = (const float4*)(sXf + t * 64);
        float sx_ = 0.f;
        #pragma unroll
        for (int j = 0; j < 16; ++j) {
            float4 v = zp[(j + t) & 15];
            sx_ += v.x + v.y + v.z + v.w;
        }
        float mu = sx_ * (1.0f / 64.0f);
        float vv = 0.f;
        #pragma unroll
        for (int j = 0; j < 16; ++j) {
            float4 v = zp[(j + t) & 15];
            float d0 = v.x - mu, d1 = v.y - mu, d2 = v.z - mu, d3 = v.w - mu;
            vv += d0*d0 + d1*d1 + d2*d2 + d3*d3;
        }
        s_mu[t] = mu;
        s_rs[t] = 1.0f / sqrtf(vv * (1.0f / 64.0f) + EPSF);
    }
    __syncthreads();
    // normalize -> lors bf16 in bufB ; xq staged in parallel
    for (int idx = t; idx < 1536; idx += 256) {
        int k = idx >> 6, e = idx & 63;
        float v = (sXf[idx] - s_mu[k]) * s_rs[k] * lnw[e] + lnb[e];
        bufB[k * 72 + e] = f2bf(v);
    }
    if (t < 128) {
        int q = t >> 6, e = t & 63;
        s_xq[t] = feats[(NSUP + b * 2 + q) * 64 + e] + tags[256 + e];
    }
    __syncthreads();

    // t1[q][s] = r1s[s] . xq[q]
    if (t < 12) {
        int q = t / 6, s = t - q * 6;
        const uint4* rp = (const uint4*)(bufB + (s * 4 + 1) * 72);
        const float* xp = s_xq + q * 64;
        float d = 0.f;
        #pragma unroll
        for (int j = 0; j < 8; ++j) {
            uint4 u = rp[j];
            const float* x = xp + j * 8;
            d += bflo(u.x)*x[0] + bfhi(u.x)*x[1] + bflo(u.y)*x[2] + bfhi(u.y)*x[3]
               + bflo(u.z)*x[4] + bfhi(u.z)*x[5] + bflo(u.w)*x[6] + bfhi(u.w)*x[7];
        }
        s_t1[t] = d;
    }
    __syncthreads();
    // h = w1 xq + sum_s l1s t1 ; ah = gelu(h)
    if (t < 128) {
        int q = t >> 6, e = t & 63;
        const uint4* wp = (const uint4*)(W1g + e * 72);
        const float* xp = s_xq + q * 64;
        float acc = 0.f;
        #pragma unroll
        for (int j = 0; j < 8; ++j) {
            uint4 u = wp[j];
            const float* x = xp + j * 8;
            acc += bflo(u.x)*x[0] + bfhi(u.x)*x[1] + bflo(u.y)*x[2] + bfhi(u.y)*x[3]
                 + bflo(u.z)*x[4] + bfhi(u.z)*x[5] + bflo(u.w)*x[6] + bfhi(u.w)*x[7];
        }
        #pragma unroll
        for (int s = 0; s < 6; ++s)
            acc += bflo((unsigned)bufB[(s * 4 + 0) * 72 + e]) * s_t1[q * 6 + s];
        s_ah[t] = gelu_f(acc);
    }
    __syncthreads();
    if (t < 12) {
        int q = t / 6, s = t - q * 6;
        const uint4* rp = (const uint4*)(bufB + (s * 4 + 3) * 72);
        const float* xp = s_ah + q * 64;
        float d = 0.f;
        #pragma unroll
        for (int j = 0; j < 8; ++j) {
            uint4 u = rp[j];
            const float* x = xp + j * 8;
            d += bflo(u.x)*x[0] + bfhi(u.x)*x[1] + bflo(u.y)*x[2] + bfhi(u.y)*x[3]
               + bflo(u.z)*x[4] + bfhi(u.z)*x[5] + bflo(u.w)*x[6] + bfhi(u.w)*x[7];
        }
        s_t2[t] = d;
    }
    __syncthreads();
    if (t < 128) {
        int q = t >> 6, e = t & 63;
        const uint4* wp = (const uint4*)(W2g + e * 72);
        const float* xp = s_ah + q * 64;
        float acc = 0.f;
        #pragma unroll
        for (int j = 0; j < 8; ++j) {
            uint4 u = wp[j];
            const float* x = xp + j * 8;
            acc += bflo(u.x)*x[0] + bfhi(u.x)*x[1] + bflo(u.y)*x[2] + bfhi(u.y)*x[3]
                 + bflo(u.z)*x[4] + bfhi(u.z)*x[5] + bflo(u.w)*x[6] + bfhi(u.w)*x[7];
        }
        #pragma unroll
        for (int s = 0; s < 6; ++s)
            acc += bflo((unsigned)bufB[(s * 4 + 2) * 72 + e]) * s_t2[q * 6 + s];
        s_yp[t] = acc;
    }
    __syncthreads();
    if (t < 4) {
        int q = t >> 1, ll = t & 1;
        const float4* ep = (const float4*)(emb + ll * 64);
        const float4* yp = (const float4*)(s_yp + q * 64);
        float d = 0.f;
        #pragma unroll
        for (int j = 0; j < 16; ++j) {
            float4 a = ep[j], x = yp[j];
            d += a.x*x.x + a.y*x.y + a.z*x.z + a.w*x.w;
        }
        s_lg[t] = d;
    }
    __syncthreads();
    if (t == 0) {
        float lsum = 0.f, corr = 0.f;
        #pragma unroll
        for (int q = 0; q < 2; ++q) {
            float l0 = s_lg[q * 2], l1 = s_lg[q * 2 + 1];
            int lab = qys[b * 2 + q];
            float m = fmaxf(l0, l1);
            float lse = m + logf(expf(l0 - m) + expf(l1 - m));
            lsum += -((lab ? l1 : l0) - lse);
            int pred = (l1 > l0) ? 1 : 0;
            corr += (pred == lab) ? 1.0f : 0.0f;
        }
        part[b] = lsum;
        part[512 + b] = corr;
    }
}

__global__ void __launch_bounds__(256) finalize_kernel(const float* __restrict__ part,
                                                       float* __restrict__ out)
{
    __shared__ float sl[256], sc[256];
    const int t = threadIdx.x;
    sl[t] = part[t] + part[t + 256];
    sc[t] = part[512 + t] + part[768 + t];
    __syncthreads();
    for (int s = 128; s > 0; s >>= 1) {
        if (t < s) { sl[t] += sl[t + s]; sc[t] += sc[t + s]; }
        __syncthreads();
    }
    if (t == 0) {
        float loss = sl[0] * (1.0f / 1024.0f);
        out[0] = loss;
        out[1] = loss;
        out[2] = 0.0f;
        out[3] = sc[0];
        out[4] = 1024.0f;
    }
}

extern "C" void kernel_launch(void* const* d_in, const int* in_sizes, int n_in,
                              void* d_out, int out_size, void* d_ws, size_t ws_size,
                              hipStream_t stream)
{
    (void)in_sizes; (void)n_in; (void)out_size; (void)ws_size;
    const float* sxs  = (const float*)d_in[1];
    const float* qxs  = (const float*)d_in[2];
    const float* c1w  = (const float*)d_in[4];
    const float* c1b  = (const float*)d_in[5];
    const float* bn1  = (const float*)d_in[6];
    const float* c2w  = (const float*)d_in[7];
    const float* c2b  = (const float*)d_in[8];
    const float* bn2  = (const float*)d_in[9];
    const float* c3w  = (const float*)d_in[10];
    const float* c3b  = (const float*)d_in[11];
    const float* bn3  = (const float*)d_in[12];
    const float* c4w  = (const float*)d_in[13];
    const float* c4b  = (const float*)d_in[14];
    const float* bn4  = (const float*)d_in[15];
    const float* lin_w= (const float*)d_in[16];
    const float* emb  = (const float*)d_in[17];
    const float* w1   = (const float*)d_in[18];
    const float* w2   = (const float*)d_in[19];
    const float* tags = (const float*)d_in[20];
    const float* rq   = (const float*)d_in[21];
    const float* rk   = (const float*)d_in[22];
    const float* rv   = (const float*)d_in[23];
    const float* ro   = (const float*)d_in[24];
    const float* lnw  = (const float*)d_in[25];
    const float* lnb  = (const float*)d_in[26];
    const int*   sys  = (const int*)d_in[27];
    const int*   qys  = (const int*)d_in[28];

    float* ws  = (float*)d_ws;
    float* out = (float*)d_out;

    precompute_kernel<<<64, 256, 0, stream>>>(c1w, c1b, bn1, c2w, c2b, bn2,
                                              c3w, c3b, bn3, c4w, c4b, bn4,
                                              w1, w2, rq, ro, ws);
    feats_kernel<<<1024, 256, 0, stream>>>(sxs, qxs, lin_w, ws, ws + WS_FEATS);
    head_kernel<<<512, 256, 0, stream>>>(emb, tags, rk, rv, lnw, lnb, sys, qys,
                                         ws, ws + WS_FEATS, ws + WS_PART);
    finalize_kernel<<<1, 256, 0, stream>>>(ws + WS_PART, out);
}